// Round 10
// baseline (877.602 us; speedup 1.0000x reference)
//
#include <hip/hip_runtime.h>
#include <hip/hip_bf16.h>

#define B_ 32
#define L_ 256
#define W_ 32
#define TILE 16
#define PSTR 40          // shorts per (row,col) position: 80B = 5*16B, b128-aligned
#define LL (L_*L_)

typedef float    floatx4 __attribute__((ext_vector_type(4)));
typedef float    floatx2 __attribute__((ext_vector_type(2)));
typedef short    shortx8 __attribute__((ext_vector_type(8)));
typedef unsigned uintx2  __attribute__((ext_vector_type(2)));
typedef unsigned uintx4  __attribute__((ext_vector_type(4)));

#if __has_builtin(__builtin_amdgcn_cvt_pk_bf16_f32)
__device__ __forceinline__ unsigned pack_bf2(float a, float b) {
    auto v = __builtin_amdgcn_cvt_pk_bf16_f32(a, b);
    return __builtin_bit_cast(unsigned, v);
}
#else
__device__ __forceinline__ unsigned pack_bf2(float a, float b) {
    unsigned ua = __float_as_uint(a);
    unsigned ub = __float_as_uint(b);
    ua += 0x7fffu + ((ua >> 16) & 1u);
    ub += 0x7fffu + ((ub >> 16) & 1u);
    return (ua >> 16) | (ub & 0xffff0000u);
}
#endif

// ---- fast GELU on a pair, sigmoid form; polynomial part in packed f32 ----
__device__ __forceinline__ unsigned gelu2_pack(float a, float b) {
    floatx2 v{a, b};
    floatx2 x2 = v * v;
    floatx2 x3 = x2 * v;
    floatx2 inner = x3 * 0.044715f + v;                 // v_pk_fma
    floatx2 targ = inner * -2.3022082299446597f;        // v_pk_mul
    float ea = __builtin_amdgcn_exp2f(targ.x);
    float eb = __builtin_amdgcn_exp2f(targ.y);
    floatx2 e{ea, eb};
    floatx2 den = e + 1.0f;                             // v_pk_add
    float ra = __builtin_amdgcn_rcpf(den.x);
    float rb = __builtin_amdgcn_rcpf(den.y);
    floatx2 g = v * floatx2{ra, rb};                    // v_pk_mul
    return pack_bf2(g.x, g.y);
}

__device__ __forceinline__ int swizzle_blk(int p) {
    return (p & 7) * 1024 + (p >> 3);
}

// 9-tap dual-half MFMA conv: first index = x (row), second = y (col)
__device__ __forceinline__ void conv9(
        const shortx8& t00, const shortx8& t01, const shortx8& t02,
        const shortx8& t10, const shortx8& t11, const shortx8& t12,
        const shortx8& t20, const shortx8& t21, const shortx8& t22,
        const shortx8 af[3][2], const float bv[2][4], floatx4 acc[2]) {
    #pragma unroll
    for (int h = 0; h < 2; ++h) {
        acc[h] = floatx4{bv[h][0], bv[h][1], bv[h][2], bv[h][3]};
        acc[h] = __builtin_amdgcn_mfma_f32_16x16x32_bf16(af[0][h], t11, acc[h], 0, 0, 0);
        acc[h] = __builtin_amdgcn_mfma_f32_16x16x32_bf16(af[1][h], t01, acc[h], 0, 0, 0);
        acc[h] = __builtin_amdgcn_mfma_f32_16x16x32_bf16(af[1][h], t21, acc[h], 0, 0, 0);
        acc[h] = __builtin_amdgcn_mfma_f32_16x16x32_bf16(af[1][h], t10, acc[h], 0, 0, 0);
        acc[h] = __builtin_amdgcn_mfma_f32_16x16x32_bf16(af[1][h], t12, acc[h], 0, 0, 0);
        acc[h] = __builtin_amdgcn_mfma_f32_16x16x32_bf16(af[2][h], t00, acc[h], 0, 0, 0);
        acc[h] = __builtin_amdgcn_mfma_f32_16x16x32_bf16(af[2][h], t02, acc[h], 0, 0, 0);
        acc[h] = __builtin_amdgcn_mfma_f32_16x16x32_bf16(af[2][h], t20, acc[h], 0, 0, 0);
        acc[h] = __builtin_amdgcn_mfma_f32_16x16x32_bf16(af[2][h], t22, acc[h], 0, 0, 0);
    }
}

__device__ __forceinline__ void gelu_pack4(const floatx4 acc[2], unsigned d[4]) {
    d[0] = gelu2_pack(acc[0][0], acc[0][1]);
    d[1] = gelu2_pack(acc[0][2], acc[0][3]);
    d[2] = gelu2_pack(acc[1][0], acc[1][1]);
    d[3] = gelu2_pack(acc[1][2], acc[1][3]);
}

__device__ __forceinline__ void build_afrag(
        const float* wc, const float* wb, const float* wa, const float* bias,
        int m, int q, shortx8 af[3][2], float bv[2][4]) {
    const float* wm[3] = { wc, wb, wa };
    #pragma unroll
    for (int f = 0; f < 3; ++f)
      #pragma unroll
      for (int h = 0; h < 2; ++h) {
        const float* row = wm[f] + (h*16 + m) * W_ + q*8;
        floatx4 r0 = *(const floatx4*)(row);
        floatx4 r1 = *(const floatx4*)(row + 4);
        union { shortx8 s; unsigned u[4]; } w;
        w.u[0] = pack_bf2(r0.x, r0.y);
        w.u[1] = pack_bf2(r0.z, r0.w);
        w.u[2] = pack_bf2(r1.x, r1.y);
        w.u[3] = pack_bf2(r1.z, r1.w);
        af[f][h] = w.s;
      }
    #pragma unroll
    for (int h = 0; h < 2; ++h)
      #pragma unroll
      for (int r = 0; r < 4; ++r)
        bv[h][r] = bias[h*16 + q*4 + r];
}

// ---------------- first layer: 1 channel -> 32 channels (site-major out) ----------------
__global__ __launch_bounds__(256) void kern_first(
        const float* __restrict__ x, float scale,
        const float* __restrict__ ci, const float* __restrict__ bi,
        const float* __restrict__ ai, const float* __restrict__ bias_i,
        unsigned short* __restrict__ hout) {
    __shared__ float tile[18*18];
    __shared__ float wC[W_], wB[W_], wA[W_], bs[W_];
    int blk = swizzle_blk(blockIdx.x);
    int b = blk >> 8;
    int t = blk & 255;
    int x0 = (t >> 4) * TILE;
    int y0 = (t & 15) * TILE;
    int tid = threadIdx.x;
    if (tid < W_) { wC[tid] = ci[tid]; wB[tid] = bi[tid]; wA[tid] = ai[tid]; bs[tid] = bias_i[tid]; }
    const float* xb = x + (size_t)b * LL;
    for (int idx = tid; idx < 18*18; idx += 256) {
        int dy = idx / 18, dx = idx % 18;
        int gx = (x0 + dy - 1) & 255;
        int gy = (y0 + dx - 1) & 255;
        tile[idx] = scale * xb[gx * L_ + gy];
    }
    __syncthreads();
    int dx = tid & 15, dy = tid >> 4;
    const float* c0 = &tile[dy * 18 + dx];
    float ctr = c0[19];
    float nb  = c0[1] + c0[37] + c0[18] + c0[20];
    float dg  = c0[0] + c0[2] + c0[36] + c0[38];
    unsigned od[16];
    #pragma unroll
    for (int o = 0; o < 16; ++o) {
        float v0 = wC[2*o]*ctr + wB[2*o]*nb + wA[2*o]*dg + bs[2*o];
        float v1 = wC[2*o+1]*ctr + wB[2*o+1]*nb + wA[2*o+1]*dg + bs[2*o+1];
        od[o] = gelu2_pack(v0, v1);
    }
    unsigned* dst = (unsigned*)(hout + (((((size_t)b << 8) | (unsigned)(x0+dy)) << 8 | (unsigned)(y0+dx)) << 5));
    *(uintx4*)(dst)      = uintx4{od[0],  od[1],  od[2],  od[3]};
    *(uintx4*)(dst + 4)  = uintx4{od[4],  od[5],  od[6],  od[7]};
    *(uintx4*)(dst + 8)  = uintx4{od[8],  od[9],  od[10], od[11]};
    *(uintx4*)(dst + 12) = uintx4{od[12], od[13], od[14], od[15]};
}

// ---------------- fused middle-layer pair: site-major in/out, strip-sliding taps ----
__global__ __launch_bounds__(256, 5) void kern_mid2(
        const unsigned short* __restrict__ hin,
        const float* __restrict__ wc1, const float* __restrict__ wb1,
        const float* __restrict__ wa1, const float* __restrict__ bias1,
        const float* __restrict__ wc2, const float* __restrict__ wb2,
        const float* __restrict__ wa2, const float* __restrict__ bias2,
        unsigned short* __restrict__ hout) {
    __shared__ unsigned short tile2[400 * PSTR];     // 32000 B -> 5 blocks/CU (161280 <= 163840)

    const int tid = threadIdx.x;
    const int blk = swizzle_blk(blockIdx.x);
    const int b  = blk >> 8;
    const int t  = blk & 255;
    const int x0 = (t >> 4) * TILE;
    const int y0 = (t & 15) * TILE;

    const unsigned short* hb = hin + ((size_t)b << 21);

    // ---- stage: pure copy, 1600 granules of 16B ----
    #pragma unroll
    for (int jj = 0; jj < 7; ++jj) {
        int j = tid + jj * 256;
        if (j < 1600) {
            int qtr = j & 3;
            int pos = j >> 2;
            int r = (pos * 3277) >> 16;     // pos / 20
            int c = pos - r * 20;
            int gx = (x0 + r - 2) & 255;
            int gy = (y0 + c - 2) & 255;
            shortx8 v = *(const shortx8*)(hb + ((((unsigned)gx << 8) | (unsigned)gy) << 5) + qtr*8);
            *(shortx8*)(tile2 + pos * PSTR + qtr * 8) = v;
        }
    }

    const int lane = tid & 63;
    const int wv   = tid >> 6;
    const int m    = lane & 15;
    const int q    = lane >> 4;

    shortx8 afrag[3][2];
    float bv[2][4];
    build_afrag(wc1, wb1, wa1, bias1, m, q, afrag, bv);

    __syncthreads();

#define LDT(tr, off) (*(const shortx8*)(tile2 + (((tr)*20 + m + (off)))*PSTR + q*8))

    // ---- layer A main: wave wv -> site rows 4wv..4wv+3, cols m (0..15) ----
    const int trow0 = wv * 4;
    shortx8 W[3][3];
    #pragma unroll
    for (int i = 0; i < 3; ++i) {
        W[i][0] = LDT(trow0 + i, 0);
        W[i][1] = LDT(trow0 + i, 1);
        W[i][2] = LDT(trow0 + i, 2);
    }
    unsigned heldA[2][4];
    #pragma unroll
    for (int rr = 0; rr < 4; ++rr) {
        const int top = rr % 3, mid = (rr + 1) % 3, bot = (rr + 2) % 3;
        floatx4 acc[2];
        conv9(W[top][0], W[top][1], W[top][2],
              W[mid][0], W[mid][1], W[mid][2],
              W[bot][0], W[bot][1], W[bot][2], afrag, bv, acc);
        unsigned d[4];
        gelu_pack4(acc, d);
        if (rr < 2) {
            heldA[rr][0] = d[0]; heldA[rr][1] = d[1];
            heldA[rr][2] = d[2]; heldA[rr][3] = d[3];
        } else {
            unsigned short* wp = tile2 + ((trow0 + rr)*20 + m)*PSTR + q*4;
            *(uintx2*)(wp)      = uintx2{d[0], d[1]};
            *(uintx2*)(wp + 16) = uintx2{d[2], d[3]};
        }
        if (rr < 3) {
            W[top][0] = LDT(trow0 + rr + 3, 0);
            W[top][1] = LDT(trow0 + rr + 3, 1);
            W[top][2] = LDT(trow0 + rr + 3, 2);
        }
    }

    // ---- layer A edges: rows 16,17 (waves 0,1) / cols 16,17 (waves 2,3) + corners (wave 2) ----
    int er0, ec0;
    if (wv == 0)      { er0 = 16; ec0 = m;  }
    else if (wv == 1) { er0 = 17; ec0 = m;  }
    else if (wv == 2) { er0 = m;  ec0 = 16; }
    else              { er0 = m;  ec0 = 17; }
    unsigned heldE[4];
    {
        shortx8 T[3][3];
        #pragma unroll
        for (int i = 0; i < 3; ++i)
          #pragma unroll
          for (int o = 0; o < 3; ++o)
            T[i][o] = *(const shortx8*)(tile2 + ((er0 + i)*20 + ec0 + o)*PSTR + q*8);
        floatx4 acc[2];
        conv9(T[0][0], T[0][1], T[0][2], T[1][0], T[1][1], T[1][2],
              T[2][0], T[2][1], T[2][2], afrag, bv, acc);
        gelu_pack4(acc, heldE);
    }
    const int heldEoff = (er0*20 + ec0)*PSTR + q*4;

    unsigned heldC[4];
    int heldCoff = 0;
    if (wv == 2) {
        int sr = 16 + ((m >> 1) & 1);
        int sc = 16 + (m & 1);
        shortx8 T[3][3];
        #pragma unroll
        for (int i = 0; i < 3; ++i)
          #pragma unroll
          for (int o = 0; o < 3; ++o)
            T[i][o] = *(const shortx8*)(tile2 + ((sr + i)*20 + sc + o)*PSTR + q*8);
        floatx4 acc[2];
        conv9(T[0][0], T[0][1], T[0][2], T[1][0], T[1][1], T[1][2],
              T[2][0], T[2][1], T[2][2], afrag, bv, acc);
        gelu_pack4(acc, heldC);
        heldCoff = (sr*20 + sc)*PSTR + q*4;
    }

    __syncthreads();   // all layer-A tap reads complete

    #pragma unroll
    for (int rr = 0; rr < 2; ++rr) {
        unsigned short* wp = tile2 + ((trow0 + rr)*20 + m)*PSTR + q*4;
        *(uintx2*)(wp)      = uintx2{heldA[rr][0], heldA[rr][1]};
        *(uintx2*)(wp + 16) = uintx2{heldA[rr][2], heldA[rr][3]};
    }
    {
        unsigned short* wp = tile2 + heldEoff;
        *(uintx2*)(wp)      = uintx2{heldE[0], heldE[1]};
        *(uintx2*)(wp + 16) = uintx2{heldE[2], heldE[3]};
    }
    if (wv == 2 && m < 4) {
        unsigned short* wp = tile2 + heldCoff;
        *(uintx2*)(wp)      = uintx2{heldC[0], heldC[1]};
        *(uintx2*)(wp + 16) = uintx2{heldC[2], heldC[3]};
    }

    build_afrag(wc2, wb2, wa2, bias2, m, q, afrag, bv);

    __syncthreads();   // mid-k+1 field complete at positions (0..17)^2

    // ---- layer B: wave wv -> site rows 4wv..4wv+3, cols m; out to global ----
    unsigned short* outb = hout + ((size_t)b << 21);
    #pragma unroll
    for (int i = 0; i < 3; ++i) {
        W[i][0] = LDT(trow0 + i, 0);
        W[i][1] = LDT(trow0 + i, 1);
        W[i][2] = LDT(trow0 + i, 2);
    }
    #pragma unroll
    for (int rr = 0; rr < 4; ++rr) {
        const int top = rr % 3, mid = (rr + 1) % 3, bot = (rr + 2) % 3;
        floatx4 acc[2];
        conv9(W[top][0], W[top][1], W[top][2],
              W[mid][0], W[mid][1], W[mid][2],
              W[bot][0], W[bot][1], W[bot][2], afrag, bv, acc);
        unsigned d[4];
        gelu_pack4(acc, d);
        unsigned short* dst = outb + ((((unsigned)(x0 + trow0 + rr) << 8) | (unsigned)(y0 + m)) << 5) + q*4;
        *(uintx2*)(dst)      = uintx2{d[0], d[1]};
        *(uintx2*)(dst + 16) = uintx2{d[2], d[3]};
        if (rr < 3) {
            W[top][0] = LDT(trow0 + rr + 3, 0);
            W[top][1] = LDT(trow0 + rr + 3, 1);
            W[top][2] = LDT(trow0 + rr + 3, 2);
        }
    }
#undef LDT
}

// ---------------- last layer: 32 -> 1 channel via row-0 MFMA, antisym ----------------
__global__ __launch_bounds__(256, 6) void kern_last(
        const unsigned short* __restrict__ hin,
        const float* __restrict__ co, const float* __restrict__ bo,
        const float* __restrict__ ao,
        float* __restrict__ out, int mode) {
    __shared__ unsigned short tile2[324 * PSTR];     // 25920 B
    const int tid = threadIdx.x;
    const int blk = swizzle_blk(blockIdx.x);
    const int b  = blk >> 8;
    const int t  = blk & 255;
    const int x0 = (t >> 4) * TILE;
    const int y0 = (t & 15) * TILE;

    const unsigned short* hb = hin + ((size_t)b << 21);
    #pragma unroll
    for (int jj = 0; jj < 6; ++jj) {
        int j = tid + jj * 256;
        if (j < 1296) {
            int qtr = j & 3;
            int pos = j >> 2;
            int r = (pos * 3641) >> 16;     // pos / 18
            int c = pos - r * 18;
            int gx = (x0 + r - 1) & 255;
            int gy = (y0 + c - 1) & 255;
            shortx8 v = *(const shortx8*)(hb + ((((unsigned)gx << 8) | (unsigned)gy) << 5) + qtr*8);
            *(shortx8*)(tile2 + pos * PSTR + qtr * 8) = v;
        }
    }

    const int lane = tid & 63;
    const int wv   = tid >> 6;
    const int m    = lane & 15;
    const int q    = lane >> 4;

    const float* wm[3] = { co, bo, ao };
    shortx8 afl[3];
    float z = (m == 0) ? 1.0f : 0.0f;
    #pragma unroll
    for (int f = 0; f < 3; ++f) {
        const float* row = wm[f] + q*8;
        floatx4 r0 = *(const floatx4*)(row);
        floatx4 r1 = *(const floatx4*)(row + 4);
        union { shortx8 s; unsigned u[4]; } w;
        w.u[0] = pack_bf2(r0.x * z, r0.y * z);
        w.u[1] = pack_bf2(r0.z * z, r0.w * z);
        w.u[2] = pack_bf2(r1.x * z, r1.y * z);
        w.u[3] = pack_bf2(r1.z * z, r1.w * z);
        afl[f] = w.s;
    }

    __syncthreads();

#define LDT18(tr, off) (*(const shortx8*)(tile2 + (((tr)*18 + m + (off)))*PSTR + q*8))
    const int trow0 = wv * 4;
    shortx8 W[3][3];
    #pragma unroll
    for (int i = 0; i < 3; ++i) {
        W[i][0] = LDT18(trow0 + i, 0);
        W[i][1] = LDT18(trow0 + i, 1);
        W[i][2] = LDT18(trow0 + i, 2);
    }
    #pragma unroll
    for (int rr = 0; rr < 4; ++rr) {
        const int top = rr % 3, mid = (rr + 1) % 3, bot = (rr + 2) % 3;
        floatx4 acc = {0.f, 0.f, 0.f, 0.f};
        acc = __builtin_amdgcn_mfma_f32_16x16x32_bf16(afl[0], W[mid][1], acc, 0, 0, 0);
        acc = __builtin_amdgcn_mfma_f32_16x16x32_bf16(afl[1], W[top][1], acc, 0, 0, 0);
        acc = __builtin_amdgcn_mfma_f32_16x16x32_bf16(afl[1], W[bot][1], acc, 0, 0, 0);
        acc = __builtin_amdgcn_mfma_f32_16x16x32_bf16(afl[1], W[mid][0], acc, 0, 0, 0);
        acc = __builtin_amdgcn_mfma_f32_16x16x32_bf16(afl[1], W[mid][2], acc, 0, 0, 0);
        acc = __builtin_amdgcn_mfma_f32_16x16x32_bf16(afl[2], W[top][0], acc, 0, 0, 0);
        acc = __builtin_amdgcn_mfma_f32_16x16x32_bf16(afl[2], W[top][2], acc, 0, 0, 0);
        acc = __builtin_amdgcn_mfma_f32_16x16x32_bf16(afl[2], W[bot][0], acc, 0, 0, 0);
        acc = __builtin_amdgcn_mfma_f32_16x16x32_bf16(afl[2], W[bot][2], acc, 0, 0, 0);
        if (q == 0) {
            size_t oidx = (size_t)b * LL + (size_t)(x0 + trow0 + rr) * L_ + (y0 + m);
            float v = 0.5f * acc[0];
            if (mode == 0) out[oidx] = v;
            else           out[oidx] = out[oidx] - v;
        }
        if (rr < 3) {
            W[top][0] = LDT18(trow0 + rr + 3, 0);
            W[top][1] = LDT18(trow0 + rr + 3, 1);
            W[top][2] = LDT18(trow0 + rr + 3, 2);
        }
    }
#undef LDT18
}

extern "C" void kernel_launch(void* const* d_in, const int* in_sizes, int n_in,
                              void* d_out, int out_size, void* d_ws, size_t ws_size,
                              hipStream_t stream) {
    const float* x      = (const float*)d_in[0];
    const float* ai     = (const float*)d_in[1];
    const float* ao     = (const float*)d_in[2];
    const float* a      = (const float*)d_in[3];
    const float* bi     = (const float*)d_in[4];
    const float* bo     = (const float*)d_in[5];
    const float* b      = (const float*)d_in[6];
    const float* ci     = (const float*)d_in[7];
    const float* co     = (const float*)d_in[8];
    const float* c      = (const float*)d_in[9];
    const float* bias_i = (const float*)d_in[10];
    const float* bias   = (const float*)d_in[11];
    float* out = (float*)d_out;

    const size_t elems = (size_t)B_ * W_ * LL;
    unsigned short* hA = (unsigned short*)d_ws;
    unsigned short* hB = hA + elems;

    dim3 grid(B_ * 256), blk(256);
    const int WW = W_ * W_;
    for (int s = 0; s < 2; ++s) {
        float scale = s ? -1.0f : 1.0f;
        kern_first<<<grid, blk, 0, stream>>>(x, scale, ci, bi, ai, bias_i, hA);
        kern_mid2<<<grid, blk, 0, stream>>>(hA,
            c, b, a, bias,
            c + WW, b + WW, a + WW, bias + W_,
            hB);
        kern_mid2<<<grid, blk, 0, stream>>>(hB,
            c + 2*WW, b + 2*WW, a + 2*WW, bias + 2*W_,
            c + 3*WW, b + 3*WW, a + 3*WW, bias + 3*W_,
            hA);
        kern_last<<<grid, blk, 0, stream>>>(hA, co, bo, ao, out, s);
    }
}

// Round 11
// 793.646 us; speedup vs baseline: 1.1058x; 1.1058x over previous
//
#include <hip/hip_runtime.h>
#include <hip/hip_bf16.h>

#define B_ 32
#define L_ 256
#define W_ 32
#define TILE 16
#define PSTR 40          // shorts per (row,col) position: 80B = 5*16B, b128-aligned
#define LL (L_*L_)

typedef float    floatx4 __attribute__((ext_vector_type(4)));
typedef float    floatx2 __attribute__((ext_vector_type(2)));
typedef short    shortx8 __attribute__((ext_vector_type(8)));
typedef unsigned uintx2  __attribute__((ext_vector_type(2)));
typedef unsigned uintx4  __attribute__((ext_vector_type(4)));

#if __has_builtin(__builtin_amdgcn_cvt_pk_bf16_f32)
__device__ __forceinline__ unsigned pack_bf2(float a, float b) {
    auto v = __builtin_amdgcn_cvt_pk_bf16_f32(a, b);
    return __builtin_bit_cast(unsigned, v);
}
#else
__device__ __forceinline__ unsigned pack_bf2(float a, float b) {
    unsigned ua = __float_as_uint(a);
    unsigned ub = __float_as_uint(b);
    ua += 0x7fffu + ((ua >> 16) & 1u);
    ub += 0x7fffu + ((ub >> 16) & 1u);
    return (ua >> 16) | (ub & 0xffff0000u);
}
#endif

// ---- fast GELU on a pair, sigmoid form; polynomial part in packed f32 ----
__device__ __forceinline__ unsigned gelu2_pack(float a, float b) {
    floatx2 v{a, b};
    floatx2 x2 = v * v;
    floatx2 x3 = x2 * v;
    floatx2 inner = x3 * 0.044715f + v;                 // v_pk_fma
    floatx2 targ = inner * -2.3022082299446597f;        // v_pk_mul
    float ea = __builtin_amdgcn_exp2f(targ.x);
    float eb = __builtin_amdgcn_exp2f(targ.y);
    floatx2 e{ea, eb};
    floatx2 den = e + 1.0f;                             // v_pk_add
    float ra = __builtin_amdgcn_rcpf(den.x);
    float rb = __builtin_amdgcn_rcpf(den.y);
    floatx2 g = v * floatx2{ra, rb};                    // v_pk_mul
    return pack_bf2(g.x, g.y);
}

__device__ __forceinline__ int swizzle_blk(int p) {
    return (p & 7) * 1024 + (p >> 3);
}

// 9-tap dual-half MFMA conv: first index = x (row), second = y (col)
__device__ __forceinline__ void conv9(
        const shortx8& t00, const shortx8& t01, const shortx8& t02,
        const shortx8& t10, const shortx8& t11, const shortx8& t12,
        const shortx8& t20, const shortx8& t21, const shortx8& t22,
        const shortx8 af[3][2], const float bv[2][4], floatx4 acc[2]) {
    #pragma unroll
    for (int h = 0; h < 2; ++h) {
        acc[h] = floatx4{bv[h][0], bv[h][1], bv[h][2], bv[h][3]};
        acc[h] = __builtin_amdgcn_mfma_f32_16x16x32_bf16(af[0][h], t11, acc[h], 0, 0, 0);
        acc[h] = __builtin_amdgcn_mfma_f32_16x16x32_bf16(af[1][h], t01, acc[h], 0, 0, 0);
        acc[h] = __builtin_amdgcn_mfma_f32_16x16x32_bf16(af[1][h], t21, acc[h], 0, 0, 0);
        acc[h] = __builtin_amdgcn_mfma_f32_16x16x32_bf16(af[1][h], t10, acc[h], 0, 0, 0);
        acc[h] = __builtin_amdgcn_mfma_f32_16x16x32_bf16(af[1][h], t12, acc[h], 0, 0, 0);
        acc[h] = __builtin_amdgcn_mfma_f32_16x16x32_bf16(af[2][h], t00, acc[h], 0, 0, 0);
        acc[h] = __builtin_amdgcn_mfma_f32_16x16x32_bf16(af[2][h], t02, acc[h], 0, 0, 0);
        acc[h] = __builtin_amdgcn_mfma_f32_16x16x32_bf16(af[2][h], t20, acc[h], 0, 0, 0);
        acc[h] = __builtin_amdgcn_mfma_f32_16x16x32_bf16(af[2][h], t22, acc[h], 0, 0, 0);
    }
}

__device__ __forceinline__ void gelu_pack4(const floatx4 acc[2], unsigned d[4]) {
    d[0] = gelu2_pack(acc[0][0], acc[0][1]);
    d[1] = gelu2_pack(acc[0][2], acc[0][3]);
    d[2] = gelu2_pack(acc[1][0], acc[1][1]);
    d[3] = gelu2_pack(acc[1][2], acc[1][3]);
}

__device__ __forceinline__ void build_afrag(
        const float* wc, const float* wb, const float* wa, const float* bias,
        int m, int q, shortx8 af[3][2], float bv[2][4]) {
    const float* wm[3] = { wc, wb, wa };
    #pragma unroll
    for (int f = 0; f < 3; ++f)
      #pragma unroll
      for (int h = 0; h < 2; ++h) {
        const float* row = wm[f] + (h*16 + m) * W_ + q*8;
        floatx4 r0 = *(const floatx4*)(row);
        floatx4 r1 = *(const floatx4*)(row + 4);
        union { shortx8 s; unsigned u[4]; } w;
        w.u[0] = pack_bf2(r0.x, r0.y);
        w.u[1] = pack_bf2(r0.z, r0.w);
        w.u[2] = pack_bf2(r1.x, r1.y);
        w.u[3] = pack_bf2(r1.z, r1.w);
        af[f][h] = w.s;
      }
    #pragma unroll
    for (int h = 0; h < 2; ++h)
      #pragma unroll
      for (int r = 0; r < 4; ++r)
        bv[h][r] = bias[h*16 + q*4 + r];
}

// ---------------- first layer: 1 channel -> 32 channels (site-major out) ----------------
__global__ __launch_bounds__(256) void kern_first(
        const float* __restrict__ x, float scale,
        const float* __restrict__ ci, const float* __restrict__ bi,
        const float* __restrict__ ai, const float* __restrict__ bias_i,
        unsigned short* __restrict__ hout) {
    __shared__ float tile[18*18];
    __shared__ float wC[W_], wB[W_], wA[W_], bs[W_];
    int blk = swizzle_blk(blockIdx.x);
    int b = blk >> 8;
    int t = blk & 255;
    int x0 = (t >> 4) * TILE;
    int y0 = (t & 15) * TILE;
    int tid = threadIdx.x;
    if (tid < W_) { wC[tid] = ci[tid]; wB[tid] = bi[tid]; wA[tid] = ai[tid]; bs[tid] = bias_i[tid]; }
    const float* xb = x + (size_t)b * LL;
    for (int idx = tid; idx < 18*18; idx += 256) {
        int dy = idx / 18, dx = idx % 18;
        int gx = (x0 + dy - 1) & 255;
        int gy = (y0 + dx - 1) & 255;
        tile[idx] = scale * xb[gx * L_ + gy];
    }
    __syncthreads();
    int dx = tid & 15, dy = tid >> 4;
    const float* c0 = &tile[dy * 18 + dx];
    float ctr = c0[19];
    float nb  = c0[1] + c0[37] + c0[18] + c0[20];
    float dg  = c0[0] + c0[2] + c0[36] + c0[38];
    unsigned od[16];
    #pragma unroll
    for (int o = 0; o < 16; ++o) {
        float v0 = wC[2*o]*ctr + wB[2*o]*nb + wA[2*o]*dg + bs[2*o];
        float v1 = wC[2*o+1]*ctr + wB[2*o+1]*nb + wA[2*o+1]*dg + bs[2*o+1];
        od[o] = gelu2_pack(v0, v1);
    }
    unsigned* dst = (unsigned*)(hout + (((((size_t)b << 8) | (unsigned)(x0+dy)) << 8 | (unsigned)(y0+dx)) << 5));
    *(uintx4*)(dst)      = uintx4{od[0],  od[1],  od[2],  od[3]};
    *(uintx4*)(dst + 4)  = uintx4{od[4],  od[5],  od[6],  od[7]};
    *(uintx4*)(dst + 8)  = uintx4{od[8],  od[9],  od[10], od[11]};
    *(uintx4*)(dst + 12) = uintx4{od[12], od[13], od[14], od[15]};
}

// ---------------- fused middle-layer pair: site-major in/out, strip-sliding taps ----
// NOTE: 4 blocks/CU, NOT 5 — R10 measured: 5 blocks/CU doubles L2/L3 miss traffic
// (FETCH 66->126MB, WRITE 131->254MB) and regresses 155->180us despite +occupancy.
__global__ __launch_bounds__(256, 4) void kern_mid2(
        const unsigned short* __restrict__ hin,
        const float* __restrict__ wc1, const float* __restrict__ wb1,
        const float* __restrict__ wa1, const float* __restrict__ bias1,
        const float* __restrict__ wc2, const float* __restrict__ wb2,
        const float* __restrict__ wa2, const float* __restrict__ bias2,
        unsigned short* __restrict__ hout) {
    __shared__ unsigned short tile2[400 * PSTR];     // 32000 B

    const int tid = threadIdx.x;
    const int blk = swizzle_blk(blockIdx.x);
    const int b  = blk >> 8;
    const int t  = blk & 255;
    const int x0 = (t >> 4) * TILE;
    const int y0 = (t & 15) * TILE;

    const unsigned short* hb = hin + ((size_t)b << 21);

    // ---- stage: pure copy, 1600 granules of 16B ----
    #pragma unroll
    for (int jj = 0; jj < 7; ++jj) {
        int j = tid + jj * 256;
        if (j < 1600) {
            int qtr = j & 3;
            int pos = j >> 2;
            int r = (pos * 3277) >> 16;     // pos / 20
            int c = pos - r * 20;
            int gx = (x0 + r - 2) & 255;
            int gy = (y0 + c - 2) & 255;
            shortx8 v = *(const shortx8*)(hb + ((((unsigned)gx << 8) | (unsigned)gy) << 5) + qtr*8);
            *(shortx8*)(tile2 + pos * PSTR + qtr * 8) = v;
        }
    }

    const int lane = tid & 63;
    const int wv   = tid >> 6;
    const int m    = lane & 15;
    const int q    = lane >> 4;

    shortx8 afrag[3][2];
    float bv[2][4];
    build_afrag(wc1, wb1, wa1, bias1, m, q, afrag, bv);

    __syncthreads();

#define LDT(tr, off) (*(const shortx8*)(tile2 + (((tr)*20 + m + (off)))*PSTR + q*8))

    // ---- layer A main: wave wv -> site rows 4wv..4wv+3, cols m (0..15) ----
    const int trow0 = wv * 4;
    shortx8 W[3][3];
    #pragma unroll
    for (int i = 0; i < 3; ++i) {
        W[i][0] = LDT(trow0 + i, 0);
        W[i][1] = LDT(trow0 + i, 1);
        W[i][2] = LDT(trow0 + i, 2);
    }
    unsigned heldA[2][4];
    #pragma unroll
    for (int rr = 0; rr < 4; ++rr) {
        const int top = rr % 3, mid = (rr + 1) % 3, bot = (rr + 2) % 3;
        floatx4 acc[2];
        conv9(W[top][0], W[top][1], W[top][2],
              W[mid][0], W[mid][1], W[mid][2],
              W[bot][0], W[bot][1], W[bot][2], afrag, bv, acc);
        unsigned d[4];
        gelu_pack4(acc, d);
        if (rr < 2) {
            heldA[rr][0] = d[0]; heldA[rr][1] = d[1];
            heldA[rr][2] = d[2]; heldA[rr][3] = d[3];
        } else {
            unsigned short* wp = tile2 + ((trow0 + rr)*20 + m)*PSTR + q*4;
            *(uintx2*)(wp)      = uintx2{d[0], d[1]};
            *(uintx2*)(wp + 16) = uintx2{d[2], d[3]};
        }
        if (rr < 3) {
            W[top][0] = LDT(trow0 + rr + 3, 0);
            W[top][1] = LDT(trow0 + rr + 3, 1);
            W[top][2] = LDT(trow0 + rr + 3, 2);
        }
    }

    // ---- layer A edges: rows 16,17 (waves 0,1) / cols 16,17 (waves 2,3) + corners (wave 2) ----
    int er0, ec0;
    if (wv == 0)      { er0 = 16; ec0 = m;  }
    else if (wv == 1) { er0 = 17; ec0 = m;  }
    else if (wv == 2) { er0 = m;  ec0 = 16; }
    else              { er0 = m;  ec0 = 17; }
    unsigned heldE[4];
    {
        shortx8 T[3][3];
        #pragma unroll
        for (int i = 0; i < 3; ++i)
          #pragma unroll
          for (int o = 0; o < 3; ++o)
            T[i][o] = *(const shortx8*)(tile2 + ((er0 + i)*20 + ec0 + o)*PSTR + q*8);
        floatx4 acc[2];
        conv9(T[0][0], T[0][1], T[0][2], T[1][0], T[1][1], T[1][2],
              T[2][0], T[2][1], T[2][2], afrag, bv, acc);
        gelu_pack4(acc, heldE);
    }
    const int heldEoff = (er0*20 + ec0)*PSTR + q*4;

    unsigned heldC[4];
    int heldCoff = 0;
    if (wv == 2) {
        int sr = 16 + ((m >> 1) & 1);
        int sc = 16 + (m & 1);
        shortx8 T[3][3];
        #pragma unroll
        for (int i = 0; i < 3; ++i)
          #pragma unroll
          for (int o = 0; o < 3; ++o)
            T[i][o] = *(const shortx8*)(tile2 + ((sr + i)*20 + sc + o)*PSTR + q*8);
        floatx4 acc[2];
        conv9(T[0][0], T[0][1], T[0][2], T[1][0], T[1][1], T[1][2],
              T[2][0], T[2][1], T[2][2], afrag, bv, acc);
        gelu_pack4(acc, heldC);
        heldCoff = (sr*20 + sc)*PSTR + q*4;
    }

    __syncthreads();   // all layer-A tap reads complete

    #pragma unroll
    for (int rr = 0; rr < 2; ++rr) {
        unsigned short* wp = tile2 + ((trow0 + rr)*20 + m)*PSTR + q*4;
        *(uintx2*)(wp)      = uintx2{heldA[rr][0], heldA[rr][1]};
        *(uintx2*)(wp + 16) = uintx2{heldA[rr][2], heldA[rr][3]};
    }
    {
        unsigned short* wp = tile2 + heldEoff;
        *(uintx2*)(wp)      = uintx2{heldE[0], heldE[1]};
        *(uintx2*)(wp + 16) = uintx2{heldE[2], heldE[3]};
    }
    if (wv == 2 && m < 4) {
        unsigned short* wp = tile2 + heldCoff;
        *(uintx2*)(wp)      = uintx2{heldC[0], heldC[1]};
        *(uintx2*)(wp + 16) = uintx2{heldC[2], heldC[3]};
    }

    build_afrag(wc2, wb2, wa2, bias2, m, q, afrag, bv);

    __syncthreads();   // mid-k+1 field complete at positions (0..17)^2

    // ---- layer B: wave wv -> site rows 4wv..4wv+3, cols m; out to global ----
    unsigned short* outb = hout + ((size_t)b << 21);
    #pragma unroll
    for (int i = 0; i < 3; ++i) {
        W[i][0] = LDT(trow0 + i, 0);
        W[i][1] = LDT(trow0 + i, 1);
        W[i][2] = LDT(trow0 + i, 2);
    }
    #pragma unroll
    for (int rr = 0; rr < 4; ++rr) {
        const int top = rr % 3, mid = (rr + 1) % 3, bot = (rr + 2) % 3;
        floatx4 acc[2];
        conv9(W[top][0], W[top][1], W[top][2],
              W[mid][0], W[mid][1], W[mid][2],
              W[bot][0], W[bot][1], W[bot][2], afrag, bv, acc);
        unsigned d[4];
        gelu_pack4(acc, d);
        unsigned short* dst = outb + ((((unsigned)(x0 + trow0 + rr) << 8) | (unsigned)(y0 + m)) << 5) + q*4;
        *(uintx2*)(dst)      = uintx2{d[0], d[1]};
        *(uintx2*)(dst + 16) = uintx2{d[2], d[3]};
        if (rr < 3) {
            W[top][0] = LDT(trow0 + rr + 3, 0);
            W[top][1] = LDT(trow0 + rr + 3, 1);
            W[top][2] = LDT(trow0 + rr + 3, 2);
        }
    }
#undef LDT
}

// ---------------- last layer: 32 -> 1 channel via row-0 MFMA, antisym ----------------
__global__ __launch_bounds__(256, 6) void kern_last(
        const unsigned short* __restrict__ hin,
        const float* __restrict__ co, const float* __restrict__ bo,
        const float* __restrict__ ao,
        float* __restrict__ out, int mode) {
    __shared__ unsigned short tile2[324 * PSTR];     // 25920 B
    const int tid = threadIdx.x;
    const int blk = swizzle_blk(blockIdx.x);
    const int b  = blk >> 8;
    const int t  = blk & 255;
    const int x0 = (t >> 4) * TILE;
    const int y0 = (t & 15) * TILE;

    const unsigned short* hb = hin + ((size_t)b << 21);
    #pragma unroll
    for (int jj = 0; jj < 6; ++jj) {
        int j = tid + jj * 256;
        if (j < 1296) {
            int qtr = j & 3;
            int pos = j >> 2;
            int r = (pos * 3641) >> 16;     // pos / 18
            int c = pos - r * 18;
            int gx = (x0 + r - 1) & 255;
            int gy = (y0 + c - 1) & 255;
            shortx8 v = *(const shortx8*)(hb + ((((unsigned)gx << 8) | (unsigned)gy) << 5) + qtr*8);
            *(shortx8*)(tile2 + pos * PSTR + qtr * 8) = v;
        }
    }

    const int lane = tid & 63;
    const int wv   = tid >> 6;
    const int m    = lane & 15;
    const int q    = lane >> 4;

    const float* wm[3] = { co, bo, ao };
    shortx8 afl[3];
    float z = (m == 0) ? 1.0f : 0.0f;
    #pragma unroll
    for (int f = 0; f < 3; ++f) {
        const float* row = wm[f] + q*8;
        floatx4 r0 = *(const floatx4*)(row);
        floatx4 r1 = *(const floatx4*)(row + 4);
        union { shortx8 s; unsigned u[4]; } w;
        w.u[0] = pack_bf2(r0.x * z, r0.y * z);
        w.u[1] = pack_bf2(r0.z * z, r0.w * z);
        w.u[2] = pack_bf2(r1.x * z, r1.y * z);
        w.u[3] = pack_bf2(r1.z * z, r1.w * z);
        afl[f] = w.s;
    }

    __syncthreads();

#define LDT18(tr, off) (*(const shortx8*)(tile2 + (((tr)*18 + m + (off)))*PSTR + q*8))
    const int trow0 = wv * 4;
    shortx8 W[3][3];
    #pragma unroll
    for (int i = 0; i < 3; ++i) {
        W[i][0] = LDT18(trow0 + i, 0);
        W[i][1] = LDT18(trow0 + i, 1);
        W[i][2] = LDT18(trow0 + i, 2);
    }
    #pragma unroll
    for (int rr = 0; rr < 4; ++rr) {
        const int top = rr % 3, mid = (rr + 1) % 3, bot = (rr + 2) % 3;
        floatx4 acc = {0.f, 0.f, 0.f, 0.f};
        acc = __builtin_amdgcn_mfma_f32_16x16x32_bf16(afl[0], W[mid][1], acc, 0, 0, 0);
        acc = __builtin_amdgcn_mfma_f32_16x16x32_bf16(afl[1], W[top][1], acc, 0, 0, 0);
        acc = __builtin_amdgcn_mfma_f32_16x16x32_bf16(afl[1], W[bot][1], acc, 0, 0, 0);
        acc = __builtin_amdgcn_mfma_f32_16x16x32_bf16(afl[1], W[mid][0], acc, 0, 0, 0);
        acc = __builtin_amdgcn_mfma_f32_16x16x32_bf16(afl[1], W[mid][2], acc, 0, 0, 0);
        acc = __builtin_amdgcn_mfma_f32_16x16x32_bf16(afl[2], W[top][0], acc, 0, 0, 0);
        acc = __builtin_amdgcn_mfma_f32_16x16x32_bf16(afl[2], W[top][2], acc, 0, 0, 0);
        acc = __builtin_amdgcn_mfma_f32_16x16x32_bf16(afl[2], W[bot][0], acc, 0, 0, 0);
        acc = __builtin_amdgcn_mfma_f32_16x16x32_bf16(afl[2], W[bot][2], acc, 0, 0, 0);
        if (q == 0) {
            size_t oidx = (size_t)b * LL + (size_t)(x0 + trow0 + rr) * L_ + (y0 + m);
            float v = 0.5f * acc[0];
            if (mode == 0) out[oidx] = v;
            else           out[oidx] = out[oidx] - v;
        }
        if (rr < 3) {
            W[top][0] = LDT18(trow0 + rr + 3, 0);
            W[top][1] = LDT18(trow0 + rr + 3, 1);
            W[top][2] = LDT18(trow0 + rr + 3, 2);
        }
    }
#undef LDT18
}

extern "C" void kernel_launch(void* const* d_in, const int* in_sizes, int n_in,
                              void* d_out, int out_size, void* d_ws, size_t ws_size,
                              hipStream_t stream) {
    const float* x      = (const float*)d_in[0];
    const float* ai     = (const float*)d_in[1];
    const float* ao     = (const float*)d_in[2];
    const float* a      = (const float*)d_in[3];
    const float* bi     = (const float*)d_in[4];
    const float* bo     = (const float*)d_in[5];
    const float* b      = (const float*)d_in[6];
    const float* ci     = (const float*)d_in[7];
    const float* co     = (const float*)d_in[8];
    const float* c      = (const float*)d_in[9];
    const float* bias_i = (const float*)d_in[10];
    const float* bias   = (const float*)d_in[11];
    float* out = (float*)d_out;

    const size_t elems = (size_t)B_ * W_ * LL;
    unsigned short* hA = (unsigned short*)d_ws;
    unsigned short* hB = hA + elems;

    dim3 grid(B_ * 256), blk(256);
    const int WW = W_ * W_;
    for (int s = 0; s < 2; ++s) {
        float scale = s ? -1.0f : 1.0f;
        kern_first<<<grid, blk, 0, stream>>>(x, scale, ci, bi, ai, bias_i, hA);
        kern_mid2<<<grid, blk, 0, stream>>>(hA,
            c, b, a, bias,
            c + WW, b + WW, a + WW, bias + W_,
            hB);
        kern_mid2<<<grid, blk, 0, stream>>>(hB,
            c + 2*WW, b + 2*WW, a + 2*WW, bias + 2*W_,
            c + 3*WW, b + 3*WW, a + 3*WW, bias + 3*W_,
            hA);
        kern_last<<<grid, blk, 0, stream>>>(hA, co, bo, ao, out, s);
    }
}